// Round 3
// baseline (773.443 us; speedup 1.0000x reference)
//
#include <hip/hip_runtime.h>
#include <hip/hip_fp16.h>
#include <cstdint>

// ---------------------------------------------------------------------------
// 3-layer GAT (PyG GATConv semantics) on MI355X.
//   CSR by dst (histogram -> 3-phase scan -> atomic scatter)
//   per layer: GEMM+alpha-fused epilogue -> per-edge online-softmax aggregate
// Layers 1-2: features gathered as fp16 (halves gather BW); logits fp32 exact.
// Layer 3: full fp32.
// ---------------------------------------------------------------------------

__global__ __launch_bounds__(256) void count_kernel(const int* __restrict__ ei,
                                                    int E, int N,
                                                    int* __restrict__ deg) {
  int g = blockIdx.x * 256 + threadIdx.x;
  if (g >= E + N) return;
  int dst = (g < E) ? ei[E + g] : (g - E);  // self-loop tail
  atomicAdd(&deg[dst], 1);
}

__global__ __launch_bounds__(256) void deg_block_reduce(const int* __restrict__ deg,
                                                        int* __restrict__ bsum, int N) {
  __shared__ int red[4];
  int b = blockIdx.x;
  int v = 0;
#pragma unroll
  for (int s = 0; s < 4; ++s) {
    int idx = b * 1024 + s * 256 + threadIdx.x;
    if (idx < N) v += deg[idx];
  }
  for (int off = 32; off; off >>= 1) v += __shfl_down(v, off);
  if ((threadIdx.x & 63) == 0) red[threadIdx.x >> 6] = v;
  __syncthreads();
  if (threadIdx.x == 0) bsum[b] = red[0] + red[1] + red[2] + red[3];
}

__global__ __launch_bounds__(1024) void small_scan(const int* __restrict__ bsum,
                                                   int* __restrict__ bpre, int NB) {
  __shared__ int buf[1024];
  int v = (threadIdx.x < NB) ? bsum[threadIdx.x] : 0;
  buf[threadIdx.x] = v;
  __syncthreads();
  for (int off = 1; off < 1024; off <<= 1) {
    int tv = (threadIdx.x >= off) ? buf[threadIdx.x - off] : 0;
    __syncthreads();
    buf[threadIdx.x] += tv;
    __syncthreads();
  }
  if (threadIdx.x < NB) bpre[threadIdx.x] = buf[threadIdx.x] - v;
}

__global__ __launch_bounds__(1024) void scan_final(const int* __restrict__ deg,
                                                   const int* __restrict__ bpre,
                                                   int* __restrict__ row_off,
                                                   int* __restrict__ cursor,
                                                   int N, int total) {
  __shared__ int buf[1024];
  int b = blockIdx.x;
  int i = b * 1024 + threadIdx.x;
  int v = (i < N) ? deg[i] : 0;
  buf[threadIdx.x] = v;
  __syncthreads();
  for (int off = 1; off < 1024; off <<= 1) {
    int tv = (threadIdx.x >= off) ? buf[threadIdx.x - off] : 0;
    __syncthreads();
    buf[threadIdx.x] += tv;
    __syncthreads();
  }
  if (i < N) {
    int ro = bpre[b] + buf[threadIdx.x] - v;  // exclusive
    row_off[i] = ro;
    cursor[i] = ro;
  }
  if (i == 0) row_off[N] = total;
}

__global__ __launch_bounds__(256) void scatter_kernel(const int* __restrict__ ei,
                                                      int E, int N,
                                                      int* __restrict__ cursor,
                                                      int* __restrict__ esrc) {
  int g = blockIdx.x * 256 + threadIdx.x;
  if (g >= E + N) return;
  int src, dst;
  if (g < E) { src = ei[g]; dst = ei[E + g]; }
  else       { src = g - E; dst = src; }
  int pos = atomicAdd(&cursor[dst], 1);
  esrc[pos] = src;
}

// fp32 GEMM  T = A@B  with fused alpha epilogue.
// BM=128 x BN tile, 256 thr, per-thread 8 x (BN/16). Each block's BN columns
// cover whole heads (head = 64 cols), so alpha dots reduce block-locally:
// per-thread partial over its TN cols, then 8(BN=128)/16(BN=64)-lane shuffle.
// HALF_OUT: write T as fp16 (gather operand for layers 1-2).
template <int BN, bool HALF_OUT>
__global__ __launch_bounds__(256) void gemm_alpha(
    const float* __restrict__ A, const float* __restrict__ B,
    void* __restrict__ Tout,
    const float* __restrict__ avec_src, const float* __restrict__ avec_dst,
    float* __restrict__ asrc, float* __restrict__ adst,
    int M, int K, int Ncol) {
  constexpr int TN = BN / 16;
  __shared__ float As[16][132];
  __shared__ float Bs[16][BN + 4];
  int tid = threadIdx.x;
  int row0 = blockIdx.x * 128, col0 = blockIdx.y * BN;
  int ty = tid >> 4, tx = tid & 15;
  int ar = tid >> 1, ak = (tid & 1) << 3;
  int arow = min(row0 + ar, M - 1);
  float acc[8][TN] = {};
  for (int kk = 0; kk < K; kk += 16) {
    const float* Ap = A + (size_t)arow * K + kk + ak;
    float4 a0 = *reinterpret_cast<const float4*>(Ap);
    float4 a1 = *reinterpret_cast<const float4*>(Ap + 4);
    As[ak + 0][ar] = a0.x; As[ak + 1][ar] = a0.y;
    As[ak + 2][ar] = a0.z; As[ak + 3][ar] = a0.w;
    As[ak + 4][ar] = a1.x; As[ak + 5][ar] = a1.y;
    As[ak + 6][ar] = a1.z; As[ak + 7][ar] = a1.w;
    if (BN == 128) {
#pragma unroll
      for (int q = 0; q < 2; ++q) {
        int lin = tid + q * 256;
        int brow = lin >> 5, bc4 = (lin & 31) << 2;
        *reinterpret_cast<float4*>(&Bs[brow][bc4]) =
            *reinterpret_cast<const float4*>(B + (size_t)(kk + brow) * Ncol + col0 + bc4);
      }
    } else {
      int brow = tid >> 4, bc4 = (tid & 15) << 2;
      *reinterpret_cast<float4*>(&Bs[brow][bc4]) =
          *reinterpret_cast<const float4*>(B + (size_t)(kk + brow) * Ncol + col0 + bc4);
    }
    __syncthreads();
#pragma unroll
    for (int k = 0; k < 16; ++k) {
      float a[8], bv[TN];
      *reinterpret_cast<float4*>(&a[0]) = *reinterpret_cast<const float4*>(&As[k][ty * 8]);
      *reinterpret_cast<float4*>(&a[4]) = *reinterpret_cast<const float4*>(&As[k][ty * 8 + 4]);
#pragma unroll
      for (int q = 0; q < TN / 4; ++q)
        *reinterpret_cast<float4*>(&bv[q * 4]) =
            *reinterpret_cast<const float4*>(&Bs[k][tx * TN + q * 4]);
#pragma unroll
      for (int i = 0; i < 8; ++i)
#pragma unroll
        for (int jn = 0; jn < TN; ++jn)
          acc[i][jn] = fmaf(a[i], bv[jn], acc[i][jn]);
    }
    __syncthreads();
  }

  // ---- alpha vectors for this thread's column segment ----
  int H = Ncol >> 6;
  int head, seg;
  if (BN == 128) { head = (col0 >> 6) + (tx >> 3); seg = (tx & 7) * 8; }
  else           { head = 0;                        seg = tx * 4; }
  float avs[TN], avd[TN];
#pragma unroll
  for (int j = 0; j < TN; ++j) {
    avs[j] = avec_src[head * 64 + seg + j];
    avd[j] = avec_dst[head * 64 + seg + j];
  }

#pragma unroll
  for (int i = 0; i < 8; ++i) {
    int r = row0 + ty * 8 + i;
    float ps = 0.f, pd = 0.f;
#pragma unroll
    for (int j = 0; j < TN; ++j) {
      ps = fmaf(acc[i][j], avs[j], ps);
      pd = fmaf(acc[i][j], avd[j], pd);
    }
    if (BN == 128) {
#pragma unroll
      for (int off = 1; off < 8; off <<= 1) {
        ps += __shfl_xor(ps, off);
        pd += __shfl_xor(pd, off);
      }
      if ((tx & 7) == 0 && r < M) { asrc[r * H + head] = ps; adst[r * H + head] = pd; }
    } else {
#pragma unroll
      for (int off = 1; off < 16; off <<= 1) {
        ps += __shfl_xor(ps, off);
        pd += __shfl_xor(pd, off);
      }
      if (tx == 0 && r < M) { asrc[r] = ps; adst[r] = pd; }
    }
    if (r < M) {
      if (HALF_OUT) {
        __half tmp[TN];
#pragma unroll
        for (int j = 0; j < TN; ++j) tmp[j] = __float2half_rn(acc[i][j]);
        if (TN == 8)
          *reinterpret_cast<uint4*>((__half*)Tout + (size_t)r * Ncol + col0 + tx * TN) =
              *reinterpret_cast<uint4*>(tmp);
        else
          *reinterpret_cast<uint2*>((__half*)Tout + (size_t)r * Ncol + col0 + tx * TN) =
              *reinterpret_cast<uint2*>(tmp);
      } else {
#pragma unroll
        for (int q = 0; q < TN / 4; ++q)
          *reinterpret_cast<float4*>((float*)Tout + (size_t)r * Ncol + col0 + tx * TN + q * 4) =
              make_float4(acc[i][q * 4], acc[i][q * 4 + 1], acc[i][q * 4 + 2], acc[i][q * 4 + 3]);
      }
    }
  }
}

// H=4 aggregate: block per dst, wave = head. Per-edge online softmax, no LDS.
template <bool ELU>
__global__ __launch_bounds__(256) void aggregate_h4(
    const __half* __restrict__ T16, const int* __restrict__ row_off,
    const int* __restrict__ esrc, const float* __restrict__ asrc,
    const float* __restrict__ adst, const float* __restrict__ bias,
    float* __restrict__ out, int N) {
  int dst = blockIdx.x;
  int h = threadIdx.x >> 6, lane = threadIdx.x & 63;
  int r0 = row_off[dst], r1 = row_off[dst + 1];
  float adj = adst[dst * 4 + h];
  const __half* base = T16 + h * 64 + lane;
  float m = -1e30f, den = 0.f, acc = 0.f;
  for (int j = r0; j < r1; ++j) {
    int s = esrc[j];
    float e = asrc[s * 4 + h] + adj;
    e = e > 0.f ? e : 0.2f * e;
    float nm = fmaxf(m, e);
    float sc = __expf(m - nm);
    float w = __expf(e - nm);
    float hv = __half2float(base[(size_t)s * 256]);
    den = fmaf(den, sc, w);
    acc = fmaf(acc, sc, w * hv);
    m = nm;
  }
  float v = acc / den + bias[threadIdx.x];
  if (ELU) v = v > 0.f ? v : expm1f(v);
  out[(size_t)dst * 256 + threadIdx.x] = v;
}

// H=1 aggregate (layer 3, fp32): wave per dst, 4 dst per block.
__global__ __launch_bounds__(256) void aggregate_h1(
    const float* __restrict__ T, const int* __restrict__ row_off,
    const int* __restrict__ esrc, const float* __restrict__ asrc,
    const float* __restrict__ adst, const float* __restrict__ bias,
    float* __restrict__ out, int N) {
  int wv = threadIdx.x >> 6, lane = threadIdx.x & 63;
  int dst = blockIdx.x * 4 + wv;
  if (dst >= N) return;
  int r0 = row_off[dst], r1 = row_off[dst + 1];
  float adj = adst[dst];
  const float* base = T + lane;
  float m = -1e30f, den = 0.f, acc = 0.f;
  for (int j = r0; j < r1; ++j) {
    int s = esrc[j];
    float e = asrc[s] + adj;
    e = e > 0.f ? e : 0.2f * e;
    float nm = fmaxf(m, e);
    float sc = __expf(m - nm);
    float w = __expf(e - nm);
    float hv = base[(size_t)s * 64];
    den = fmaf(den, sc, w);
    acc = fmaf(acc, sc, w * hv);
    m = nm;
  }
  out[(size_t)dst * 64 + lane] = acc / den + bias[lane];
}

extern "C" void kernel_launch(void* const* d_in, const int* in_sizes, int n_in,
                              void* d_out, int out_size, void* d_ws, size_t ws_size,
                              hipStream_t stream) {
  const float* x   = (const float*)d_in[0];
  const int*   ei  = (const int*)d_in[1];
  const float* W1  = (const float*)d_in[2];
  const float* as1 = (const float*)d_in[3];
  const float* ad1 = (const float*)d_in[4];
  const float* b1  = (const float*)d_in[5];
  const float* W2  = (const float*)d_in[6];
  const float* as2 = (const float*)d_in[7];
  const float* ad2 = (const float*)d_in[8];
  const float* b2  = (const float*)d_in[9];
  const float* W3  = (const float*)d_in[10];
  const float* as3 = (const float*)d_in[11];
  const float* ad3 = (const float*)d_in[12];
  const float* b3  = (const float*)d_in[13];
  float* out = (float*)d_out;

  const int Fin = 128, H = 4, C = 64, HC = H * C;  // 256
  const int N = in_sizes[0] / Fin;
  const int E = in_sizes[1] / 2;
  const int ET = E + N;
  const int NB = (N + 1023) / 1024;

  // workspace layout (~95 MB)
  __half* T16 = (__half*)d_ws;                     // [N, 256] fp16
  float* T32  = (float*)(T16 + (size_t)N * HC);    // [N, 64] fp32 (layer 3)
  float* F    = T32 + (size_t)N * C;               // [N, 256]
  float* asrc = F + (size_t)N * HC;                // [N, H]
  float* adst = asrc + (size_t)N * H;              // [N, H]
  int* deg     = (int*)(adst + (size_t)N * H);
  int* row_off = deg + N;
  int* cursor  = row_off + (N + 1);
  int* bsum    = cursor + N;                       // [NB]
  int* bpre    = bsum + NB;                        // [NB]
  int* esrc    = bpre + NB;                        // [E + N]

  // ---- CSR by destination ----
  hipMemsetAsync(deg, 0, N * sizeof(int), stream);
  count_kernel<<<(ET + 255) / 256, 256, 0, stream>>>(ei, E, N, deg);
  deg_block_reduce<<<NB, 256, 0, stream>>>(deg, bsum, N);
  small_scan<<<1, 1024, 0, stream>>>(bsum, bpre, NB);
  scan_final<<<NB, 1024, 0, stream>>>(deg, bpre, row_off, cursor, N, ET);
  scatter_kernel<<<(ET + 255) / 256, 256, 0, stream>>>(ei, E, N, cursor, esrc);

  dim3 g1((N + 127) / 128, HC / 128);
  // ---- Layer 1: 128 -> 4x64 (concat) + ELU ----
  gemm_alpha<128, true><<<g1, 256, 0, stream>>>(x, W1, T16, as1, ad1, asrc, adst, N, Fin, HC);
  aggregate_h4<true><<<N, 256, 0, stream>>>(T16, row_off, esrc, asrc, adst, b1, F, N);

  // ---- Layer 2: 256 -> 4x64 (concat) + ELU ----
  gemm_alpha<128, true><<<g1, 256, 0, stream>>>(F, W2, T16, as2, ad2, asrc, adst, N, HC, HC);
  aggregate_h4<true><<<N, 256, 0, stream>>>(T16, row_off, esrc, asrc, adst, b2, F, N);

  // ---- Layer 3: 256 -> 1x64 (mean over 1 head == identity) ----
  gemm_alpha<64, false><<<dim3((N + 127) / 128, 1), 256, 0, stream>>>(
      F, W3, T32, as3, ad3, asrc, adst, N, HC, C);
  aggregate_h1<<<(N + 3) / 4, 256, 0, stream>>>(T32, row_off, esrc, asrc, adst, b3, out, N);
}

// Round 4
// 573.635 us; speedup vs baseline: 1.3483x; 1.3483x over previous
//
#include <hip/hip_runtime.h>
#include <hip/hip_fp16.h>
#include <cstdint>

// ---------------------------------------------------------------------------
// 3-layer GAT (PyG GATConv semantics) on MI355X.
//   CSR by dst (histogram -> 3-phase scan -> atomic scatter)
//   per layer: fp32 GEMM + fused-alpha epilogue (fp16 feature out)
//              -> chunk-parallel online-softmax aggregate (fp16 gathers)
// Logit path stays fp32 end-to-end; only gathered features are fp16.
// ---------------------------------------------------------------------------

__global__ __launch_bounds__(256) void count_kernel(const int* __restrict__ ei,
                                                    int E, int N,
                                                    int* __restrict__ deg) {
  int g = blockIdx.x * 256 + threadIdx.x;
  if (g >= E + N) return;
  int dst = (g < E) ? ei[E + g] : (g - E);  // self-loop tail
  atomicAdd(&deg[dst], 1);
}

__global__ __launch_bounds__(256) void deg_block_reduce(const int* __restrict__ deg,
                                                        int* __restrict__ bsum, int N) {
  __shared__ int red[4];
  int b = blockIdx.x;
  int v = 0;
#pragma unroll
  for (int s = 0; s < 4; ++s) {
    int idx = b * 1024 + s * 256 + threadIdx.x;
    if (idx < N) v += deg[idx];
  }
  for (int off = 32; off; off >>= 1) v += __shfl_down(v, off);
  if ((threadIdx.x & 63) == 0) red[threadIdx.x >> 6] = v;
  __syncthreads();
  if (threadIdx.x == 0) bsum[b] = red[0] + red[1] + red[2] + red[3];
}

__global__ __launch_bounds__(1024) void small_scan(const int* __restrict__ bsum,
                                                   int* __restrict__ bpre, int NB) {
  __shared__ int buf[1024];
  int v = (threadIdx.x < NB) ? bsum[threadIdx.x] : 0;
  buf[threadIdx.x] = v;
  __syncthreads();
  for (int off = 1; off < 1024; off <<= 1) {
    int tv = (threadIdx.x >= off) ? buf[threadIdx.x - off] : 0;
    __syncthreads();
    buf[threadIdx.x] += tv;
    __syncthreads();
  }
  if (threadIdx.x < NB) bpre[threadIdx.x] = buf[threadIdx.x] - v;
}

__global__ __launch_bounds__(1024) void scan_final(const int* __restrict__ deg,
                                                   const int* __restrict__ bpre,
                                                   int* __restrict__ row_off,
                                                   int* __restrict__ cursor,
                                                   int N, int total) {
  __shared__ int buf[1024];
  int b = blockIdx.x;
  int i = b * 1024 + threadIdx.x;
  int v = (i < N) ? deg[i] : 0;
  buf[threadIdx.x] = v;
  __syncthreads();
  for (int off = 1; off < 1024; off <<= 1) {
    int tv = (threadIdx.x >= off) ? buf[threadIdx.x - off] : 0;
    __syncthreads();
    buf[threadIdx.x] += tv;
    __syncthreads();
  }
  if (i < N) {
    int ro = bpre[b] + buf[threadIdx.x] - v;  // exclusive
    row_off[i] = ro;
    cursor[i] = ro;
  }
  if (i == 0) row_off[N] = total;
}

__global__ __launch_bounds__(256) void scatter_kernel(const int* __restrict__ ei,
                                                      int E, int N,
                                                      int* __restrict__ cursor,
                                                      int* __restrict__ esrc) {
  int g = blockIdx.x * 256 + threadIdx.x;
  if (g >= E + N) return;
  int src, dst;
  if (g < E) { src = ei[g]; dst = ei[E + g]; }
  else       { src = g - E; dst = src; }
  int pos = atomicAdd(&cursor[dst], 1);
  esrc[pos] = src;
}

// fp32 GEMM  T = A@B  with fused alpha epilogue; T written as fp16.
// BM=128 x BN tile, 256 thr, per-thread 8 x (BN/16). K-step 16.
template <int BN>
__global__ __launch_bounds__(256) void gemm_alpha(
    const float* __restrict__ A, const float* __restrict__ B,
    __half* __restrict__ Tout,
    const float* __restrict__ avec_src, const float* __restrict__ avec_dst,
    float* __restrict__ asrc, float* __restrict__ adst,
    int M, int K, int Ncol) {
  constexpr int TN = BN / 16;
  __shared__ float As[16][132];
  __shared__ float Bs[16][BN + 4];
  int tid = threadIdx.x;
  int row0 = blockIdx.x * 128, col0 = blockIdx.y * BN;
  int ty = tid >> 4, tx = tid & 15;
  int ar = tid >> 1, ak = (tid & 1) << 3;
  int arow = min(row0 + ar, M - 1);
  float acc[8][TN] = {};
  for (int kk = 0; kk < K; kk += 16) {
    const float* Ap = A + (size_t)arow * K + kk + ak;
    float4 a0 = *reinterpret_cast<const float4*>(Ap);
    float4 a1 = *reinterpret_cast<const float4*>(Ap + 4);
    As[ak + 0][ar] = a0.x; As[ak + 1][ar] = a0.y;
    As[ak + 2][ar] = a0.z; As[ak + 3][ar] = a0.w;
    As[ak + 4][ar] = a1.x; As[ak + 5][ar] = a1.y;
    As[ak + 6][ar] = a1.z; As[ak + 7][ar] = a1.w;
    if (BN == 128) {
#pragma unroll
      for (int q = 0; q < 2; ++q) {
        int lin = tid + q * 256;
        int brow = lin >> 5, bc4 = (lin & 31) << 2;
        *reinterpret_cast<float4*>(&Bs[brow][bc4]) =
            *reinterpret_cast<const float4*>(B + (size_t)(kk + brow) * Ncol + col0 + bc4);
      }
    } else {
      int brow = tid >> 4, bc4 = (tid & 15) << 2;
      *reinterpret_cast<float4*>(&Bs[brow][bc4]) =
          *reinterpret_cast<const float4*>(B + (size_t)(kk + brow) * Ncol + col0 + bc4);
    }
    __syncthreads();
#pragma unroll
    for (int k = 0; k < 16; ++k) {
      float a[8], bv[TN];
      *reinterpret_cast<float4*>(&a[0]) = *reinterpret_cast<const float4*>(&As[k][ty * 8]);
      *reinterpret_cast<float4*>(&a[4]) = *reinterpret_cast<const float4*>(&As[k][ty * 8 + 4]);
#pragma unroll
      for (int q = 0; q < TN / 4; ++q)
        *reinterpret_cast<float4*>(&bv[q * 4]) =
            *reinterpret_cast<const float4*>(&Bs[k][tx * TN + q * 4]);
#pragma unroll
      for (int i = 0; i < 8; ++i)
#pragma unroll
        for (int jn = 0; jn < TN; ++jn)
          acc[i][jn] = fmaf(a[i], bv[jn], acc[i][jn]);
    }
    __syncthreads();
  }

  // ---- fused alpha dots (fp32 exact) ----
  int H = Ncol >> 6;
  int head, seg;
  if (BN == 128) { head = (col0 >> 6) + (tx >> 3); seg = (tx & 7) * 8; }
  else           { head = 0;                        seg = tx * 4; }
  float avs[TN], avd[TN];
#pragma unroll
  for (int j = 0; j < TN; ++j) {
    avs[j] = avec_src[head * 64 + seg + j];
    avd[j] = avec_dst[head * 64 + seg + j];
  }

#pragma unroll
  for (int i = 0; i < 8; ++i) {
    int r = row0 + ty * 8 + i;
    float ps = 0.f, pd = 0.f;
#pragma unroll
    for (int j = 0; j < TN; ++j) {
      ps = fmaf(acc[i][j], avs[j], ps);
      pd = fmaf(acc[i][j], avd[j], pd);
    }
    if (BN == 128) {
#pragma unroll
      for (int off = 1; off < 8; off <<= 1) {
        ps += __shfl_xor(ps, off);
        pd += __shfl_xor(pd, off);
      }
      if ((tx & 7) == 0 && r < M) { asrc[r * H + head] = ps; adst[r * H + head] = pd; }
    } else {
#pragma unroll
      for (int off = 1; off < 16; off <<= 1) {
        ps += __shfl_xor(ps, off);
        pd += __shfl_xor(pd, off);
      }
      if (tx == 0 && r < M) { asrc[r] = ps; adst[r] = pd; }
    }
    if (r < M) {
      __half tmp[TN];
#pragma unroll
      for (int j = 0; j < TN; ++j) tmp[j] = __float2half_rn(acc[i][j]);
      if (TN == 8)
        *reinterpret_cast<uint4*>(Tout + (size_t)r * Ncol + col0 + tx * TN) =
            *reinterpret_cast<uint4*>(tmp);
      else
        *reinterpret_cast<uint2*>(Tout + (size_t)r * Ncol + col0 + tx * TN) =
            *reinterpret_cast<uint2*>(tmp);
    }
  }
}

// H=4 aggregate: block per dst, wave = head. Chunk-parallel online softmax:
// 64 edge logits computed in parallel by 256 threads, per-wave shuffle
// reductions, then a tight fma loop over fp16 feature rows.
template <bool ELU>
__global__ __launch_bounds__(256) void aggregate_h4(
    const __half* __restrict__ T16, const int* __restrict__ row_off,
    const int* __restrict__ esrc, const float* __restrict__ asrc,
    const float* __restrict__ adst, const float* __restrict__ bias,
    float* __restrict__ out, int N) {
  __shared__ int s_src[64];
  __shared__ float s_w[64][5];  // pad to stride 5 -> conflict-free col reads
  int dst = blockIdx.x;
  int t = threadIdx.x;
  int h = t >> 6, lane = t & 63;
  int j = t >> 2, hh = t & 3;  // staging role
  int r0 = row_off[dst], deg = row_off[dst + 1] - r0;
  float adj_c = adst[dst * 4 + h];   // compute role
  float adj_s = adst[dst * 4 + hh];  // staging role
  const __half* base = T16 + h * 64 + lane;
  float m = -1e30f, den = 0.f, acc = 0.f;
  for (int b0 = 0; b0 < deg; b0 += 64) {
    int cnt = min(64, deg - b0);
    __syncthreads();
    if (j < cnt) {
      int s = esrc[r0 + b0 + j];
      if (hh == 0) s_src[j] = s;
      float e = asrc[s * 4 + hh] + adj_s;
      s_w[j][hh] = e > 0.f ? e : 0.2f * e;
    }
    __syncthreads();
    // each wave consumes (and later overwrites) only column h
    float ev = (lane < cnt) ? s_w[lane][h] : -1e30f;
    float cm = ev;
    for (int off = 32; off; off >>= 1) cm = fmaxf(cm, __shfl_xor(cm, off));
    float nm = fmaxf(m, cm);
    float sc = __expf(m - nm);  // first chunk: exp(-inf) = 0
    float w = (lane < cnt) ? __expf(ev - nm) : 0.f;
    float ws = w;
    for (int off = 32; off; off >>= 1) ws += __shfl_xor(ws, off);
    den = fmaf(den, sc, ws);
    acc *= sc;
    m = nm;
    s_w[lane][h] = w;  // wave-local write/read, no barrier needed
#pragma unroll 4
    for (int j2 = 0; j2 < cnt; ++j2)
      acc = fmaf(s_w[j2][h], __half2float(base[(size_t)s_src[j2] * 256]), acc);
  }
  float v = acc / den + bias[t];
  if (ELU) v = v > 0.f ? v : expm1f(v);
  out[(size_t)dst * 256 + t] = v;
}

// H=1 aggregate (layer 3): wave per dst, 4 dst/block, fp16 features,
// weights broadcast by shuffle. No LDS.
__global__ __launch_bounds__(256) void aggregate_h1(
    const __half* __restrict__ T16, const int* __restrict__ row_off,
    const int* __restrict__ esrc, const float* __restrict__ asrc,
    const float* __restrict__ adst, const float* __restrict__ bias,
    float* __restrict__ out, int N) {
  int wv = threadIdx.x >> 6, lane = threadIdx.x & 63;
  int dst = blockIdx.x * 4 + wv;
  if (dst >= N) return;
  int r0 = row_off[dst], deg = row_off[dst + 1] - r0;
  float adj = adst[dst];
  const __half* base = T16 + lane;
  float m = -1e30f, den = 0.f, acc = 0.f;
  for (int b0 = 0; b0 < deg; b0 += 64) {
    int cnt = min(64, deg - b0);
    int s = 0;
    float ev = -1e30f;
    if (lane < cnt) {
      s = esrc[r0 + b0 + lane];
      float e = asrc[s] + adj;
      ev = e > 0.f ? e : 0.2f * e;
    }
    float cm = ev;
    for (int off = 32; off; off >>= 1) cm = fmaxf(cm, __shfl_xor(cm, off));
    float nm = fmaxf(m, cm);
    float sc = __expf(m - nm);
    float w = (lane < cnt) ? __expf(ev - nm) : 0.f;
    float ws = w;
    for (int off = 32; off; off >>= 1) ws += __shfl_xor(ws, off);
    den = fmaf(den, sc, ws);
    acc *= sc;
    m = nm;
#pragma unroll 4
    for (int j2 = 0; j2 < cnt; ++j2) {
      int sj = __shfl(s, j2);
      float wj = __shfl(w, j2);
      acc = fmaf(wj, __half2float(base[(size_t)sj * 64]), acc);
    }
  }
  out[(size_t)dst * 64 + lane] = acc / den + bias[lane];
}

extern "C" void kernel_launch(void* const* d_in, const int* in_sizes, int n_in,
                              void* d_out, int out_size, void* d_ws, size_t ws_size,
                              hipStream_t stream) {
  const float* x   = (const float*)d_in[0];
  const int*   ei  = (const int*)d_in[1];
  const float* W1  = (const float*)d_in[2];
  const float* as1 = (const float*)d_in[3];
  const float* ad1 = (const float*)d_in[4];
  const float* b1  = (const float*)d_in[5];
  const float* W2  = (const float*)d_in[6];
  const float* as2 = (const float*)d_in[7];
  const float* ad2 = (const float*)d_in[8];
  const float* b2  = (const float*)d_in[9];
  const float* W3  = (const float*)d_in[10];
  const float* as3 = (const float*)d_in[11];
  const float* ad3 = (const float*)d_in[12];
  const float* b3  = (const float*)d_in[13];
  float* out = (float*)d_out;

  const int Fin = 128, H = 4, C = 64, HC = H * C;  // 256
  const int N = in_sizes[0] / Fin;
  const int E = in_sizes[1] / 2;
  const int ET = E + N;
  const int NB = (N + 1023) / 1024;

  // workspace layout
  __half* T16   = (__half*)d_ws;                      // [N, 256] fp16
  __half* T16L3 = T16 + (size_t)N * HC;               // [N, 64] fp16
  float* F    = (float*)(T16L3 + (size_t)N * C);      // [N, 256]
  float* asrc = F + (size_t)N * HC;                   // [N, H]
  float* adst = asrc + (size_t)N * H;                 // [N, H]
  int* deg     = (int*)(adst + (size_t)N * H);
  int* row_off = deg + N;
  int* cursor  = row_off + (N + 1);
  int* bsum    = cursor + N;                          // [NB]
  int* bpre    = bsum + NB;                           // [NB]
  int* esrc    = bpre + NB;                           // [E + N]

  // ---- CSR by destination ----
  hipMemsetAsync(deg, 0, N * sizeof(int), stream);
  count_kernel<<<(ET + 255) / 256, 256, 0, stream>>>(ei, E, N, deg);
  deg_block_reduce<<<NB, 256, 0, stream>>>(deg, bsum, N);
  small_scan<<<1, 1024, 0, stream>>>(bsum, bpre, NB);
  scan_final<<<NB, 1024, 0, stream>>>(deg, bpre, row_off, cursor, N, ET);
  scatter_kernel<<<(ET + 255) / 256, 256, 0, stream>>>(ei, E, N, cursor, esrc);

  dim3 g1((N + 127) / 128, HC / 128);
  // ---- Layer 1: 128 -> 4x64 (concat) + ELU ----
  gemm_alpha<128><<<g1, 256, 0, stream>>>(x, W1, T16, as1, ad1, asrc, adst, N, Fin, HC);
  aggregate_h4<true><<<N, 256, 0, stream>>>(T16, row_off, esrc, asrc, adst, b1, F, N);

  // ---- Layer 2: 256 -> 4x64 (concat) + ELU ----
  gemm_alpha<128><<<g1, 256, 0, stream>>>(F, W2, T16, as2, ad2, asrc, adst, N, HC, HC);
  aggregate_h4<true><<<N, 256, 0, stream>>>(T16, row_off, esrc, asrc, adst, b2, F, N);

  // ---- Layer 3: 256 -> 1x64 (mean over 1 head == identity) ----
  gemm_alpha<64><<<dim3((N + 127) / 128, 1), 256, 0, stream>>>(
      F, W3, T16L3, as3, ad3, asrc, adst, N, HC, C);
  aggregate_h1<<<(N + 3) / 4, 256, 0, stream>>>(T16L3, row_off, esrc, asrc, adst, b3, out, N);
}

// Round 5
// 522.474 us; speedup vs baseline: 1.4803x; 1.0979x over previous
//
#include <hip/hip_runtime.h>
#include <hip/hip_fp16.h>
#include <cstdint>

// ---------------------------------------------------------------------------
// 3-layer GAT (PyG GATConv semantics) on MI355X.
//   CSR by dst (histogram -> 3-phase scan -> atomic scatter)
//   per layer: fp32 GEMM + fused-alpha epilogue (fp16 feature out)
//              -> chunk-parallel online-softmax aggregate with 4-edge/wave
//                 vectorized fp16 gathers (uint2 per lane, 16 lanes per edge)
// Logit path stays fp32 end-to-end; only gathered features are fp16.
// ---------------------------------------------------------------------------

__global__ __launch_bounds__(256) void count_kernel(const int* __restrict__ ei,
                                                    int E, int N,
                                                    int* __restrict__ deg) {
  int g = blockIdx.x * 256 + threadIdx.x;
  if (g >= E + N) return;
  int dst = (g < E) ? ei[E + g] : (g - E);  // self-loop tail
  atomicAdd(&deg[dst], 1);
}

__global__ __launch_bounds__(256) void deg_block_reduce(const int* __restrict__ deg,
                                                        int* __restrict__ bsum, int N) {
  __shared__ int red[4];
  int b = blockIdx.x;
  int v = 0;
#pragma unroll
  for (int s = 0; s < 4; ++s) {
    int idx = b * 1024 + s * 256 + threadIdx.x;
    if (idx < N) v += deg[idx];
  }
  for (int off = 32; off; off >>= 1) v += __shfl_down(v, off);
  if ((threadIdx.x & 63) == 0) red[threadIdx.x >> 6] = v;
  __syncthreads();
  if (threadIdx.x == 0) bsum[b] = red[0] + red[1] + red[2] + red[3];
}

__global__ __launch_bounds__(1024) void small_scan(const int* __restrict__ bsum,
                                                   int* __restrict__ bpre, int NB) {
  __shared__ int buf[1024];
  int v = (threadIdx.x < NB) ? bsum[threadIdx.x] : 0;
  buf[threadIdx.x] = v;
  __syncthreads();
  for (int off = 1; off < 1024; off <<= 1) {
    int tv = (threadIdx.x >= off) ? buf[threadIdx.x - off] : 0;
    __syncthreads();
    buf[threadIdx.x] += tv;
    __syncthreads();
  }
  if (threadIdx.x < NB) bpre[threadIdx.x] = buf[threadIdx.x] - v;
}

__global__ __launch_bounds__(1024) void scan_final(const int* __restrict__ deg,
                                                   const int* __restrict__ bpre,
                                                   int* __restrict__ row_off,
                                                   int* __restrict__ cursor,
                                                   int N, int total) {
  __shared__ int buf[1024];
  int b = blockIdx.x;
  int i = b * 1024 + threadIdx.x;
  int v = (i < N) ? deg[i] : 0;
  buf[threadIdx.x] = v;
  __syncthreads();
  for (int off = 1; off < 1024; off <<= 1) {
    int tv = (threadIdx.x >= off) ? buf[threadIdx.x - off] : 0;
    __syncthreads();
    buf[threadIdx.x] += tv;
    __syncthreads();
  }
  if (i < N) {
    int ro = bpre[b] + buf[threadIdx.x] - v;  // exclusive
    row_off[i] = ro;
    cursor[i] = ro;
  }
  if (i == 0) row_off[N] = total;
}

__global__ __launch_bounds__(256) void scatter_kernel(const int* __restrict__ ei,
                                                      int E, int N,
                                                      int* __restrict__ cursor,
                                                      int* __restrict__ esrc) {
  int g = blockIdx.x * 256 + threadIdx.x;
  if (g >= E + N) return;
  int src, dst;
  if (g < E) { src = ei[g]; dst = ei[E + g]; }
  else       { src = g - E; dst = src; }
  int pos = atomicAdd(&cursor[dst], 1);
  esrc[pos] = src;
}

// fp32 GEMM  T = A@B  with fused alpha epilogue; T written as fp16.
// BM=128 x BN tile, 256 thr, per-thread 8 x (BN/16). K-step 16.
template <int BN>
__global__ __launch_bounds__(256) void gemm_alpha(
    const float* __restrict__ A, const float* __restrict__ B,
    __half* __restrict__ Tout,
    const float* __restrict__ avec_src, const float* __restrict__ avec_dst,
    float* __restrict__ asrc, float* __restrict__ adst,
    int M, int K, int Ncol) {
  constexpr int TN = BN / 16;
  __shared__ float As[16][132];
  __shared__ float Bs[16][BN + 4];
  int tid = threadIdx.x;
  int row0 = blockIdx.x * 128, col0 = blockIdx.y * BN;
  int ty = tid >> 4, tx = tid & 15;
  int ar = tid >> 1, ak = (tid & 1) << 3;
  int arow = min(row0 + ar, M - 1);
  float acc[8][TN] = {};
  for (int kk = 0; kk < K; kk += 16) {
    const float* Ap = A + (size_t)arow * K + kk + ak;
    float4 a0 = *reinterpret_cast<const float4*>(Ap);
    float4 a1 = *reinterpret_cast<const float4*>(Ap + 4);
    As[ak + 0][ar] = a0.x; As[ak + 1][ar] = a0.y;
    As[ak + 2][ar] = a0.z; As[ak + 3][ar] = a0.w;
    As[ak + 4][ar] = a1.x; As[ak + 5][ar] = a1.y;
    As[ak + 6][ar] = a1.z; As[ak + 7][ar] = a1.w;
    if (BN == 128) {
#pragma unroll
      for (int q = 0; q < 2; ++q) {
        int lin = tid + q * 256;
        int brow = lin >> 5, bc4 = (lin & 31) << 2;
        *reinterpret_cast<float4*>(&Bs[brow][bc4]) =
            *reinterpret_cast<const float4*>(B + (size_t)(kk + brow) * Ncol + col0 + bc4);
      }
    } else {
      int brow = tid >> 4, bc4 = (tid & 15) << 2;
      *reinterpret_cast<float4*>(&Bs[brow][bc4]) =
          *reinterpret_cast<const float4*>(B + (size_t)(kk + brow) * Ncol + col0 + bc4);
    }
    __syncthreads();
#pragma unroll
    for (int k = 0; k < 16; ++k) {
      float a[8], bv[TN];
      *reinterpret_cast<float4*>(&a[0]) = *reinterpret_cast<const float4*>(&As[k][ty * 8]);
      *reinterpret_cast<float4*>(&a[4]) = *reinterpret_cast<const float4*>(&As[k][ty * 8 + 4]);
#pragma unroll
      for (int q = 0; q < TN / 4; ++q)
        *reinterpret_cast<float4*>(&bv[q * 4]) =
            *reinterpret_cast<const float4*>(&Bs[k][tx * TN + q * 4]);
#pragma unroll
      for (int i = 0; i < 8; ++i)
#pragma unroll
        for (int jn = 0; jn < TN; ++jn)
          acc[i][jn] = fmaf(a[i], bv[jn], acc[i][jn]);
    }
    __syncthreads();
  }

  // ---- fused alpha dots (fp32 exact) ----
  int H = Ncol >> 6;
  int head, seg;
  if (BN == 128) { head = (col0 >> 6) + (tx >> 3); seg = (tx & 7) * 8; }
  else           { head = 0;                        seg = tx * 4; }
  float avs[TN], avd[TN];
#pragma unroll
  for (int j = 0; j < TN; ++j) {
    avs[j] = avec_src[head * 64 + seg + j];
    avd[j] = avec_dst[head * 64 + seg + j];
  }

#pragma unroll
  for (int i = 0; i < 8; ++i) {
    int r = row0 + ty * 8 + i;
    float ps = 0.f, pd = 0.f;
#pragma unroll
    for (int j = 0; j < TN; ++j) {
      ps = fmaf(acc[i][j], avs[j], ps);
      pd = fmaf(acc[i][j], avd[j], pd);
    }
    if (BN == 128) {
#pragma unroll
      for (int off = 1; off < 8; off <<= 1) {
        ps += __shfl_xor(ps, off);
        pd += __shfl_xor(pd, off);
      }
      if ((tx & 7) == 0 && r < M) { asrc[r * H + head] = ps; adst[r * H + head] = pd; }
    } else {
#pragma unroll
      for (int off = 1; off < 16; off <<= 1) {
        ps += __shfl_xor(ps, off);
        pd += __shfl_xor(pd, off);
      }
      if (tx == 0 && r < M) { asrc[r] = ps; adst[r] = pd; }
    }
    if (r < M) {
      __half tmp[TN];
#pragma unroll
      for (int j = 0; j < TN; ++j) tmp[j] = __float2half_rn(acc[i][j]);
      if (TN == 8)
        *reinterpret_cast<uint4*>(Tout + (size_t)r * Ncol + col0 + tx * TN) =
            *reinterpret_cast<uint4*>(tmp);
      else
        *reinterpret_cast<uint2*>(Tout + (size_t)r * Ncol + col0 + tx * TN) =
            *reinterpret_cast<uint2*>(tmp);
    }
  }
}

// H=4 aggregate: block per dst, wave = head. Chunk-parallel online softmax;
// gather phase: 4 lane-groups of 16, group g handles edge i*4+g, each lane
// loads uint2 (4 fp16 channels) -> one wave-iter moves 4 edges. float4 acc,
// cross-group reduce at the end.
template <bool ELU>
__global__ __launch_bounds__(256) void aggregate_h4(
    const __half* __restrict__ T16, const int* __restrict__ row_off,
    const int* __restrict__ esrc, const float* __restrict__ asrc,
    const float* __restrict__ adst, const float* __restrict__ bias,
    float* __restrict__ out, int N) {
  __shared__ int s_src[64];
  __shared__ float s_w[64][5];  // pad stride 5 -> conflict-free
  int dst = blockIdx.x;
  int t = threadIdx.x;
  int h = t >> 6, lane = t & 63;
  int g = lane >> 4, l = lane & 15;  // gather group / lane-in-group
  int j = t >> 2, hh = t & 3;        // staging role
  int r0 = row_off[dst], deg = row_off[dst + 1] - r0;
  float adj_s = adst[dst * 4 + hh];
  const __half* base = T16 + h * 64 + l * 4;  // + s*256 per edge
  float m = -1e30f, den = 0.f;
  float ax = 0.f, ay = 0.f, az = 0.f, aw = 0.f;
  for (int b0 = 0; b0 < deg; b0 += 64) {
    int cnt = min(64, deg - b0);
    __syncthreads();
    if (j < cnt) {
      int s = esrc[r0 + b0 + j];
      if (hh == 0) s_src[j] = s;
      float e = asrc[s * 4 + hh] + adj_s;
      s_w[j][hh] = e > 0.f ? e : 0.2f * e;
    }
    __syncthreads();
    float ev = (lane < cnt) ? s_w[lane][h] : -1e30f;
    float cm = ev;
    for (int off = 32; off; off >>= 1) cm = fmaxf(cm, __shfl_xor(cm, off));
    float nm = fmaxf(m, cm);
    float sc = __expf(m - nm);  // first chunk: exp(-inf) = 0
    float w = (lane < cnt) ? __expf(ev - nm) : 0.f;
    float ws = w;
    for (int off = 32; off; off >>= 1) ws += __shfl_xor(ws, off);
    den = fmaf(den, sc, ws);
    ax *= sc; ay *= sc; az *= sc; aw *= sc;
    m = nm;
    s_w[lane][h] = w;  // wave-local write/read (in-order DS per wave)
    int iters = (cnt + 3) >> 2;
#pragma unroll 4
    for (int i = 0; i < iters; ++i) {
      int e4 = i * 4 + g;
      int idx = e4 < cnt ? e4 : 0;
      float wj = s_w[idx][h];
      if (e4 >= cnt) wj = 0.f;
      int sj = s_src[idx];
      uint2 raw = *reinterpret_cast<const uint2*>(base + (size_t)sj * 256);
      __half2 p0 = *reinterpret_cast<__half2*>(&raw.x);
      __half2 p1 = *reinterpret_cast<__half2*>(&raw.y);
      float2 f0 = __half22float2(p0);
      float2 f1 = __half22float2(p1);
      ax = fmaf(wj, f0.x, ax);
      ay = fmaf(wj, f0.y, ay);
      az = fmaf(wj, f1.x, az);
      aw = fmaf(wj, f1.y, aw);
    }
  }
  // cross-group reduction (groups differ in lane bits 4-5)
#pragma unroll
  for (int off = 16; off < 64; off <<= 1) {
    ax += __shfl_xor(ax, off);
    ay += __shfl_xor(ay, off);
    az += __shfl_xor(az, off);
    aw += __shfl_xor(aw, off);
  }
  if (lane < 16) {
    int c0 = h * 64 + l * 4;
    float rd = 1.f / den;
    float4 v;
    v.x = ax * rd + bias[c0 + 0];
    v.y = ay * rd + bias[c0 + 1];
    v.z = az * rd + bias[c0 + 2];
    v.w = aw * rd + bias[c0 + 3];
    if (ELU) {
      v.x = v.x > 0.f ? v.x : expm1f(v.x);
      v.y = v.y > 0.f ? v.y : expm1f(v.y);
      v.z = v.z > 0.f ? v.z : expm1f(v.z);
      v.w = v.w > 0.f ? v.w : expm1f(v.w);
    }
    *reinterpret_cast<float4*>(&out[(size_t)dst * 256 + c0]) = v;
  }
}

// H=1 aggregate (layer 3): wave per dst, 4 dst/block, same 4-edge/wave
// vectorized gather; weights/indices broadcast via per-lane-index shuffle.
__global__ __launch_bounds__(256) void aggregate_h1(
    const __half* __restrict__ T16, const int* __restrict__ row_off,
    const int* __restrict__ esrc, const float* __restrict__ asrc,
    const float* __restrict__ adst, const float* __restrict__ bias,
    float* __restrict__ out, int N) {
  int wv = threadIdx.x >> 6, lane = threadIdx.x & 63;
  int g = lane >> 4, l = lane & 15;
  int dst = blockIdx.x * 4 + wv;
  if (dst >= N) return;
  int r0 = row_off[dst], deg = row_off[dst + 1] - r0;
  float adj = adst[dst];
  const __half* base = T16 + l * 4;  // + s*64 per edge
  float m = -1e30f, den = 0.f;
  float ax = 0.f, ay = 0.f, az = 0.f, aw = 0.f;
  for (int b0 = 0; b0 < deg; b0 += 64) {
    int cnt = min(64, deg - b0);
    int s = 0;
    float ev = -1e30f;
    if (lane < cnt) {
      s = esrc[r0 + b0 + lane];
      float e = asrc[s] + adj;
      ev = e > 0.f ? e : 0.2f * e;
    }
    float cm = ev;
    for (int off = 32; off; off >>= 1) cm = fmaxf(cm, __shfl_xor(cm, off));
    float nm = fmaxf(m, cm);
    float sc = __expf(m - nm);
    float w = (lane < cnt) ? __expf(ev - nm) : 0.f;
    float ws = w;
    for (int off = 32; off; off >>= 1) ws += __shfl_xor(ws, off);
    den = fmaf(den, sc, ws);
    ax *= sc; ay *= sc; az *= sc; aw *= sc;
    m = nm;
    int iters = (cnt + 3) >> 2;
#pragma unroll 4
    for (int i = 0; i < iters; ++i) {
      int e4 = i * 4 + g;
      int idx = e4 < cnt ? e4 : 0;
      float wj = __shfl(w, idx);
      if (e4 >= cnt) wj = 0.f;
      int sj = __shfl(s, idx);
      uint2 raw = *reinterpret_cast<const uint2*>(base + (size_t)sj * 64);
      __half2 p0 = *reinterpret_cast<__half2*>(&raw.x);
      __half2 p1 = *reinterpret_cast<__half2*>(&raw.y);
      float2 f0 = __half22float2(p0);
      float2 f1 = __half22float2(p1);
      ax = fmaf(wj, f0.x, ax);
      ay = fmaf(wj, f0.y, ay);
      az = fmaf(wj, f1.x, az);
      aw = fmaf(wj, f1.y, aw);
    }
  }
#pragma unroll
  for (int off = 16; off < 64; off <<= 1) {
    ax += __shfl_xor(ax, off);
    ay += __shfl_xor(ay, off);
    az += __shfl_xor(az, off);
    aw += __shfl_xor(aw, off);
  }
  if (lane < 16) {
    float rd = 1.f / den;
    float4 v;
    v.x = ax * rd + bias[l * 4 + 0];
    v.y = ay * rd + bias[l * 4 + 1];
    v.z = az * rd + bias[l * 4 + 2];
    v.w = aw * rd + bias[l * 4 + 3];
    *reinterpret_cast<float4*>(&out[(size_t)dst * 64 + l * 4]) = v;
  }
}

extern "C" void kernel_launch(void* const* d_in, const int* in_sizes, int n_in,
                              void* d_out, int out_size, void* d_ws, size_t ws_size,
                              hipStream_t stream) {
  const float* x   = (const float*)d_in[0];
  const int*   ei  = (const int*)d_in[1];
  const float* W1  = (const float*)d_in[2];
  const float* as1 = (const float*)d_in[3];
  const float* ad1 = (const float*)d_in[4];
  const float* b1  = (const float*)d_in[5];
  const float* W2  = (const float*)d_in[6];
  const float* as2 = (const float*)d_in[7];
  const float* ad2 = (const float*)d_in[8];
  const float* b2  = (const float*)d_in[9];
  const float* W3  = (const float*)d_in[10];
  const float* as3 = (const float*)d_in[11];
  const float* ad3 = (const float*)d_in[12];
  const float* b3  = (const float*)d_in[13];
  float* out = (float*)d_out;

  const int Fin = 128, H = 4, C = 64, HC = H * C;  // 256
  const int N = in_sizes[0] / Fin;
  const int E = in_sizes[1] / 2;
  const int ET = E + N;
  const int NB = (N + 1023) / 1024;

  // workspace layout
  __half* T16   = (__half*)d_ws;                      // [N, 256] fp16
  __half* T16L3 = T16 + (size_t)N * HC;               // [N, 64] fp16
  float* F    = (float*)(T16L3 + (size_t)N * C);      // [N, 256]
  float* asrc = F + (size_t)N * HC;                   // [N, H]
  float* adst = asrc + (size_t)N * H;                 // [N, H]
  int* deg     = (int*)(adst + (size_t)N * H);
  int* row_off = deg + N;
  int* cursor  = row_off + (N + 1);
  int* bsum    = cursor + N;                          // [NB]
  int* bpre    = bsum + NB;                           // [NB]
  int* esrc    = bpre + NB;                           // [E + N]

  // ---- CSR by destination ----
  hipMemsetAsync(deg, 0, N * sizeof(int), stream);
  count_kernel<<<(ET + 255) / 256, 256, 0, stream>>>(ei, E, N, deg);
  deg_block_reduce<<<NB, 256, 0, stream>>>(deg, bsum, N);
  small_scan<<<1, 1024, 0, stream>>>(bsum, bpre, NB);
  scan_final<<<NB, 1024, 0, stream>>>(deg, bpre, row_off, cursor, N, ET);
  scatter_kernel<<<(ET + 255) / 256, 256, 0, stream>>>(ei, E, N, cursor, esrc);

  dim3 g1((N + 127) / 128, HC / 128);
  // ---- Layer 1: 128 -> 4x64 (concat) + ELU ----
  gemm_alpha<128><<<g1, 256, 0, stream>>>(x, W1, T16, as1, ad1, asrc, adst, N, Fin, HC);
  aggregate_h4<true><<<N, 256, 0, stream>>>(T16, row_off, esrc, asrc, adst, b1, F, N);

  // ---- Layer 2: 256 -> 4x64 (concat) + ELU ----
  gemm_alpha<128><<<g1, 256, 0, stream>>>(F, W2, T16, as2, ad2, asrc, adst, N, HC, HC);
  aggregate_h4<true><<<N, 256, 0, stream>>>(T16, row_off, esrc, asrc, adst, b2, F, N);

  // ---- Layer 3: 256 -> 1x64 (mean over 1 head == identity) ----
  gemm_alpha<64><<<dim3((N + 127) / 128, 1), 256, 0, stream>>>(
      F, W3, T16L3, as3, ad3, asrc, adst, N, HC, C);
  aggregate_h1<<<(N + 3) / 4, 256, 0, stream>>>(T16L3, row_off, esrc, asrc, adst, b3, out, N);
}